// Round 5
// baseline (616.108 us; speedup 1.0000x reference)
//
#include <hip/hip_runtime.h>
#include <hip/hip_bf16.h>
#include <stdint.h>

typedef __attribute__((ext_vector_type(8)))  __bf16 bf16x8;
typedef __attribute__((ext_vector_type(4)))  float  f32x4;
typedef __attribute__((ext_vector_type(16))) float  f32x16;

#define IN_F   4096
#define OUT_F  4096
#define M_ROWS 16384   // 8 * 2048

static __device__ __forceinline__ unsigned short f2bf(float f) {
    unsigned int u = __float_as_uint(f);
    u += 0x7FFFu + ((u >> 16) & 1u);   // round-to-nearest-even
    return (unsigned short)(u >> 16);
}

// ---------------------------------------------------------------------------
// Kernel 1: fused prep.
//   blocks [0, WBLK): build full weight (OUT_F x IN_F) bf16 into wb
//   blocks [WBLK, NBLK): convert x fp32 -> bf16 into xbuf
// ---------------------------------------------------------------------------
#define PREP_WBLK 1366
#define PREP_NBLK 4096

__global__ __launch_bounds__(256) void prep_kernel(
    const float* __restrict__ weight, const float* __restrict__ leafs,
    const float* __restrict__ x,
    unsigned short* __restrict__ wb, unsigned short* __restrict__ xbuf)
{
    const int t = threadIdx.x;
    if (blockIdx.x < PREP_WBLK) {
        __shared__ float s[4][8][8];
        {
            const int o = t >> 6, a = (t >> 3) & 7, b = t & 7;
            float acc = 0.f;
            #pragma unroll
            for (int r = 0; r < 8; ++r)
                acc += leafs[o * 512 + r * 64 + a * 8 + b];
            s[o][a][b] = acc;
        }
        __syncthreads();

        const int total = (OUT_F * IN_F) / 8;
        for (int idx = blockIdx.x * 256 + t; idx < total; idx += PREP_WBLK * 256) {
            const int n  = idx >> 9;
            const int kg = idx & 511;
            const int n0 = n >> 9, n1 = (n >> 6) & 7, n2 = (n >> 3) & 7, n3 = n & 7;
            const int k0 = kg >> 6, k1 = (kg >> 3) & 7, k2 = kg & 7;
            const float p = s[0][k0][n0] * s[1][k1][n1] * s[2][k2][n2];
            const float4* wp = (const float4*)(weight + (size_t)n * IN_F + kg * 8);
            const float4 w0 = wp[0], w1 = wp[1];
            const float wv[8] = {w0.x, w0.y, w0.z, w0.w, w1.x, w1.y, w1.z, w1.w};
            unsigned int pk[4];
            #pragma unroll
            for (int j = 0; j < 4; ++j) {
                unsigned int lo = f2bf(wv[2*j]   + p * s[3][2*j]  [n3]);
                unsigned int hi = f2bf(wv[2*j+1] + p * s[3][2*j+1][n3]);
                pk[j] = lo | (hi << 16);
            }
            *reinterpret_cast<uint4*>(wb + (size_t)n * IN_F + kg * 8) =
                make_uint4(pk[0], pk[1], pk[2], pk[3]);
        }
    } else {
        const long long n8 = (long long)M_ROWS * IN_F / 8;
        const int xblocks = PREP_NBLK - PREP_WBLK;
        for (long long idx = (long long)(blockIdx.x - PREP_WBLK) * 256 + t;
             idx < n8; idx += (long long)xblocks * 256) {
            const float4* xp = (const float4*)(x + idx * 8);
            const float4 a = xp[0], b = xp[1];
            const float v[8] = {a.x, a.y, a.z, a.w, b.x, b.y, b.z, b.w};
            unsigned int pk[4];
            #pragma unroll
            for (int j = 0; j < 4; ++j)
                pk[j] = (unsigned int)f2bf(v[2*j]) | ((unsigned int)f2bf(v[2*j+1]) << 16);
            *reinterpret_cast<uint4*>(xbuf + idx * 8) =
                make_uint4(pk[0], pk[1], pk[2], pk[3]);
        }
    }
}

// ---------------------------------------------------------------------------
// Kernel 2: 256x256 GEMM on mfma_f32_32x32x16_bf16, 4-phase in-phase schedule.
// 512 thr = 8 waves (2M x 4N); per-wave 128x64 out = acc[4][2] f32x16.
// LDS: A panels [2buf][2 half][128 rows][128 B] at 0; B same at 65536. 128KiB.
// Swizzle: byte (r, c) stored at r*128 + (c ^ ((r&7)<<4)); staged linearly by
// global_load_lds from inverse-swizzled global sources (same involution).
// Phase = { ds_reads; GLLs; barrier; lgkmcnt(0); sched_barrier; setprio(1);
//           8 MFMA; setprio(0); [vmcnt(0) ph3 only]; barrier }.
// GLLs: ph0 stages A halves of next tile, ph1 stages B halves. vmcnt(0) at
// ph3 end has 2.5-3.5 phases of cover; first reads of next buf occur after
// the following barrier.
// ---------------------------------------------------------------------------
#define BK 64
#define NT 64

#define GLL(src, dst) __builtin_amdgcn_global_load_lds( \
    (const __attribute__((address_space(1))) void*)(src), \
    (__attribute__((address_space(3))) void*)(dst), 16, 0, 0)

#define SB0  __builtin_amdgcn_sched_barrier(0)
#define BAR  __builtin_amdgcn_s_barrier()
#define PRI1 __builtin_amdgcn_s_setprio(1)
#define PRI0 __builtin_amdgcn_s_setprio(0)
#define WLG0 asm volatile("s_waitcnt lgkmcnt(0)" ::: "memory")
#define WVM0 asm volatile("s_waitcnt vmcnt(0)" ::: "memory")

#define STAGE_A(b, h, ko) do { \
    GLL(pA[h] + (ko),             ldsb + (b)*32768 + (h)*16384 + t*16); \
    GLL(pA[h] + 64*IN_F + (ko),   ldsb + (b)*32768 + (h)*16384 + t*16 + 8192); } while(0)
#define STAGE_B(b, h, ko) do { \
    GLL(pB[h] + (ko),             ldsb + 65536 + (b)*32768 + (h)*16384 + t*16); \
    GLL(pB[h] + 64*IN_F + (ko),   ldsb + 65536 + (b)*32768 + (h)*16384 + t*16 + 8192); } while(0)

// A fragment reads: quadrant Q (fm = 2Q+i), k-half KH (ks = 2KH+j)
#define ARD(Q, KH) do { _Pragma("unroll") \
    for (int i_ = 0; i_ < 2; ++i_) { _Pragma("unroll") \
    for (int j_ = 0; j_ < 2; ++j_) \
        aF[i_][j_] = *(const bf16x8*)(aPan + ((Q)*2 + i_)*4096 + \
                     (aOff ^ ((((KH)*2 + j_)) << 5))); } } while(0)
#define BRD(KH) do { _Pragma("unroll") \
    for (int n_ = 0; n_ < 2; ++n_) { _Pragma("unroll") \
    for (int j_ = 0; j_ < 2; ++j_) \
        bFr[n_][j_] = *(const bf16x8*)(bPan + n_*4096 + \
                      (bOff ^ ((((KH)*2 + j_)) << 5))); } } while(0)
#define MM32(Q) do { _Pragma("unroll") \
    for (int i_ = 0; i_ < 2; ++i_) { _Pragma("unroll") \
    for (int n_ = 0; n_ < 2; ++n_) { _Pragma("unroll") \
    for (int j_ = 0; j_ < 2; ++j_) \
        acc[(Q)*2 + i_][n_] = __builtin_amdgcn_mfma_f32_32x32x16_bf16( \
            aF[i_][j_], bFr[n_][j_], acc[(Q)*2 + i_][n_], 0, 0, 0); } } } while(0)

#define TILE32(BUF, KO, PF) do { \
    const char* aPan = ldsb + (BUF)*32768 + wr*16384; \
    const char* bPan = ldsb + 65536 + (BUF)*32768 + (wcn >> 1)*16384; \
    /* ph0: Q0,KH0 */ \
    ARD(0, 0); BRD(0); \
    if (PF) { STAGE_A((BUF)^1, 0, KO); STAGE_A((BUF)^1, 1, KO); } \
    BAR; WLG0; SB0; PRI1; MM32(0); PRI0; BAR; \
    /* ph1: Q1,KH0 */ \
    ARD(1, 0); \
    if (PF) { STAGE_B((BUF)^1, 0, KO); STAGE_B((BUF)^1, 1, KO); } \
    BAR; WLG0; SB0; PRI1; MM32(1); PRI0; BAR; \
    /* ph2: Q0,KH1 */ \
    ARD(0, 1); BRD(1); \
    BAR; WLG0; SB0; PRI1; MM32(0); PRI0; BAR; \
    /* ph3: Q1,KH1 */ \
    ARD(1, 1); \
    BAR; WLG0; SB0; PRI1; MM32(1); PRI0; \
    if (PF) { WVM0; } \
    BAR; \
} while (0)

__global__ __launch_bounds__(512, 2) void gemm32_kernel(
    const unsigned short* __restrict__ xb,   // bf16 x [M_ROWS][IN_F]
    const unsigned short* __restrict__ wb,   // bf16 W [OUT_F][IN_F]
    const float* __restrict__ bias,
    float* __restrict__ out)
{
    __shared__ unsigned short lds_us[65536];   // 128 KiB
    char* const ldsb = (char*)lds_us;

    const int t    = threadIdx.x;
    const int wave = t >> 6;
    const int lane = t & 63;
    const int ln31 = lane & 31;
    const int lhi  = lane >> 5;          // 0..1
    const int wr   = wave >> 2;          // 0..1  (M half)
    const int wcn  = wave & 3;           // 0..3  (N quarter)

    // XCD-chunked swizzle; bn-major within chunk keeps the A slice L2-hot.
    const int bid  = blockIdx.x;
    const int swzb = (bid & 7) * 128 + (bid >> 3);
    const int bm   = (swzb >> 4) * 256;   // 64 M-tiles
    const int bn   = (swzb & 15) * 256;   // 16 N-tiles

    // staging: thread t stages 16B chunks t and t+512 of each panel (linear
    // LDS dest). chunk c: row r=c>>3, slot=c&7; source slot' = slot ^ (r&7).
    const int r1  = t >> 3;                   // 0..63 (chunk2: +64, same r&7)
    const int slp = (t & 7) ^ (r1 & 7);
    const unsigned short* pA[2] = {
        xb + (size_t)(bm + r1) * IN_F + slp * 8,
        xb + (size_t)(bm + 128 + r1) * IN_F + slp * 8 };
    const unsigned short* pB[2] = {
        wb + (size_t)(bn + r1) * IN_F + slp * 8,
        wb + (size_t)(bn + 128 + r1) * IN_F + slp * 8 };

    // read-side bases (swizzled): c0 spreads 32 rows uniformly over 8 slots
    const int c0   = ((lhi ^ (ln31 & 7)) << 4);
    const int aOff = ln31 * 128 + c0;
    const int bOff = ((wcn & 1) * 64 + ln31) * 128 + c0;

    f32x16 acc[4][2] = {};
    bf16x8 aF[2][2], bFr[2][2];

    // prologue: stage all 4 panels of tile 0, drain, sync.
    STAGE_A(0, 0, 0); STAGE_A(0, 1, 0); STAGE_B(0, 0, 0); STAGE_B(0, 1, 0);
    WVM0; BAR;

    #pragma unroll 1
    for (int tt = 0; tt < NT - 2; tt += 2) {
        TILE32(0, (tt + 1) * BK, true);
        TILE32(1, (tt + 2) * BK, true);
    }
    TILE32(0, (NT - 1) * BK, true);   // tile 62, stages tile 63
    TILE32(1, 0, false);              // tile 63

    // ---- epilogue: C/D col = lane&31, row = (reg&3) + 8*(reg>>2) + 4*lhi ----
    #pragma unroll
    for (int fn = 0; fn < 2; ++fn) {
        const int col = bn + wcn * 64 + fn * 32 + ln31;
        const float bv = bias[col];
        #pragma unroll
        for (int fm = 0; fm < 4; ++fm) {
            const int rb = bm + wr * 128 + fm * 32 + 4 * lhi;
            #pragma unroll
            for (int reg = 0; reg < 16; ++reg) {
                const int row = rb + (reg & 3) + 8 * (reg >> 2);
                out[(size_t)row * OUT_F + col] = acc[fm][fn][reg] + bv;
            }
        }
    }
}

// ---------------------------------------------------------------------------
// Fallback GEMM (round-1 structure) for small workspace.
// ---------------------------------------------------------------------------
#define FBM 128
#define FBN 128
#define FBK 32

__global__ __launch_bounds__(256) void gemm_fb_kernel(
    const float* __restrict__ xf,
    const unsigned short* __restrict__ wb,
    const float* __restrict__ bias,
    float* __restrict__ out)
{
    __shared__ unsigned short As[FBM * FBK];
    __shared__ unsigned short Bs[FBN * FBK];

    const int t    = threadIdx.x;
    const int wave = t >> 6;
    const int lane = t & 63;
    const int lr   = lane & 15;
    const int kq   = lane >> 4;
    const int wr   = wave >> 1;
    const int wc   = wave & 1;

    const int bm = blockIdx.x * FBM;
    const int bn = blockIdx.y * FBN;
    const int srow = t >> 2;
    const int scol = (t & 3) * 8;

    f32x4 acc[4][4] = {};

    for (int kt = 0; kt < IN_F; kt += FBK) {
        #pragma unroll
        for (int g = 0; g < 2; ++g) {
            const int row = srow + g * 64;
            const float4* xp = (const float4*)(xf + (size_t)(bm + row) * IN_F + kt + scol);
            const float4 a0 = xp[0], a1 = xp[1];
            const float v[8] = {a0.x, a0.y, a0.z, a0.w, a1.x, a1.y, a1.z, a1.w};
            unsigned int pk[4];
            #pragma unroll
            for (int j = 0; j < 4; ++j)
                pk[j] = (unsigned int)f2bf(v[2*j]) | ((unsigned int)f2bf(v[2*j+1]) << 16);
            *reinterpret_cast<uint4*>(&As[row * FBK + scol]) =
                make_uint4(pk[0], pk[1], pk[2], pk[3]);
        }
        {
            const unsigned short* gb0 = wb + (size_t)(bn + srow) * IN_F + kt + scol;
            const unsigned short* gb1 = gb0 + (size_t)64 * IN_F;
            GLL(gb0, Bs + srow * FBK + scol);
            GLL(gb1, Bs + (64 + srow) * FBK + scol);
        }
        __syncthreads();

        bf16x8 af[4], bfr[4];
        #pragma unroll
        for (int m = 0; m < 4; ++m)
            af[m] = *reinterpret_cast<const bf16x8*>(As + (wr * 64 + m * 16 + lr) * FBK + kq * 8);
        #pragma unroll
        for (int n = 0; n < 4; ++n)
            bfr[n] = *reinterpret_cast<const bf16x8*>(Bs + (wc * 64 + n * 16 + lr) * FBK + kq * 8);

        #pragma unroll
        for (int m = 0; m < 4; ++m)
            #pragma unroll
            for (int n = 0; n < 4; ++n)
                acc[m][n] = __builtin_amdgcn_mfma_f32_16x16x32_bf16(af[m], bfr[n], acc[m][n], 0, 0, 0);

        __syncthreads();
    }

    const int crow0 = kq * 4;
    #pragma unroll
    for (int n = 0; n < 4; ++n) {
        const int col = bn + wc * 64 + n * 16 + lr;
        const float bv = bias[col];
        #pragma unroll
        for (int m = 0; m < 4; ++m) {
            const int rowb = bm + wr * 64 + m * 16 + crow0;
            #pragma unroll
            for (int j = 0; j < 4; ++j)
                out[(size_t)(rowb + j) * OUT_F + col] = acc[m][n][j] + bv;
        }
    }
}

// ---------------------------------------------------------------------------
extern "C" void kernel_launch(void* const* d_in, const int* in_sizes, int n_in,
                              void* d_out, int out_size, void* d_ws, size_t ws_size,
                              hipStream_t stream) {
    const float* x      = (const float*)d_in[0];
    const float* weight = (const float*)d_in[1];
    const float* bias   = (const float*)d_in[2];
    const float* leafs  = (const float*)d_in[3];
    float* out = (float*)d_out;

    unsigned short* wb = (unsigned short*)d_ws;
    unsigned short* xbuf = (unsigned short*)((char*)d_ws +
                           (size_t)OUT_F * IN_F * sizeof(unsigned short));

    const size_t need_full = (size_t)OUT_F * IN_F * 2 + (size_t)M_ROWS * IN_F * 2;
    const bool full = ws_size >= need_full;

    if (full) {
        prep_kernel<<<dim3(PREP_NBLK), dim3(256), 0, stream>>>(
            weight, leafs, x, wb, xbuf);
        gemm32_kernel<<<dim3((M_ROWS / 256) * (OUT_F / 256)), dim3(512), 0, stream>>>(
            xbuf, wb, bias, out);
    } else {
        prep_kernel<<<dim3(PREP_WBLK), dim3(256), 0, stream>>>(
            weight, leafs, x, wb, xbuf);
        gemm_fb_kernel<<<dim3(M_ROWS / FBM, OUT_F / FBN), dim3(256), 0, stream>>>(
            x, wb, bias, out);
    }
}